// Round 11
// baseline (180.280 us; speedup 1.0000x reference)
//
#include <hip/hip_runtime.h>
#include <cstdint>
#include <cstddef>

#define LRALPHA 0.1f
static constexpr int NR = 8192;      // N and Na
static constexpr int EF = 256;
static constexpr int IN_F = 512;
static constexpr int OUT_F = 512;
static constexpr int KP2 = 1024;     // fp16 split-2, k'-interleaved [ah,al]
static constexpr int NCH = 128;      // chunks for column scans
static constexpr int CHR = 64;       // rows per chunk (NCH*CHR = 8192)

typedef __attribute__((ext_vector_type(8))) _Float16 f16x8;
typedef __attribute__((ext_vector_type(4))) float f32x4;

// ---- fused prep: s1/s2 dots (0..4095) + B pack (4096..5119) + Wh zero (5120..5631) ----
__global__ __launch_bounds__(256) void k_prep(const float* __restrict__ feat_edge,
                                              const float* __restrict__ feat_edge_a,
                                              const float* __restrict__ att,
                                              const float* __restrict__ W,
                                              float* __restrict__ s1,
                                              float* __restrict__ s2,
                                              short* __restrict__ B3t,
                                              float* __restrict__ Wh) {
  int b = blockIdx.x;
  if (b < 4096) {
    int vrow = b * 4 + (threadIdx.x >> 6);
    int lane = threadIdx.x & 63;
    const float* feat; const float* av; float* outp; int row;
    if (vrow < NR) { row = vrow; feat = feat_edge; av = att; outp = s1; }
    else { row = vrow - NR; feat = feat_edge_a; av = att + EF; outp = s2; }
    float4 f = reinterpret_cast<const float4*>(feat + (size_t)row * EF)[lane];
    float4 a = reinterpret_cast<const float4*>(av)[lane];
    float d = f.x * a.x + f.y * a.y + f.z * a.z + f.w * a.w;
#pragma unroll
    for (int off = 32; off > 0; off >>= 1) d += __shfl_xor(d, off);
    if (lane == 0) outp[row] = d;
  } else if (b < 5120) {
    int i = (b - 4096) * 256 + threadIdx.x;  // < 512*512
    int n = i >> 9, k = i & 511;
    float x = W[(size_t)k * OUT_F + n];
    _Float16 h = (_Float16)x;
    unsigned short u = __builtin_bit_cast(unsigned short, h);
    unsigned int w = (unsigned int)u | ((unsigned int)u << 16);
    *reinterpret_cast<unsigned int*>(B3t + (size_t)n * KP2 + 2 * k) = w;
  } else {
    // zero Wh (atomic accumulation target); re-done every launch -> graph-safe
    float4 z = {0.f, 0.f, 0.f, 0.f};
    size_t base = (size_t)(b - 5120) * 2048;
#pragma unroll
    for (int it = 0; it < 8; ++it)
      reinterpret_cast<float4*>(Wh)[base + it * 256 + threadIdx.x] = z;
  }
}

// ---- GEMM (K-split x2, atomic combine) + rank, one launch ----
// Gemm blocks [0,2048): 64x64 tile, BK'=64, 8 iters, dbuf LDS with XOR swizzle
// (row8 ^= slot) -> conflict-free ds_write_b128 AND ds_read_b128, while global
// reads stay 8x128B-run coalesced. 5 blocks/CU (32KB LDS) for TLP.
// Rank blocks [2048,2304): rank-by-counting on LDS-staged s2 (rotation swizzle).
struct SReg2 { float4 a0, a1; int4 b0, b1; };

__global__ __launch_bounds__(256, 5) void k_gemmrank(const float* __restrict__ A,
                                                     const short* __restrict__ B3t,
                                                     float* __restrict__ Wh,
                                                     const float* __restrict__ s2,
                                                     float* __restrict__ s2s, int* __restrict__ perm,
                                                     float* __restrict__ eaA, float* __restrict__ ebA) {
  __shared__ int4 smem[2048];   // 32 KB, unioned across branches
  const int tid = threadIdx.x;
  int bid = blockIdx.x;
  if (bid < 2048) {
    short* lA = (short*)smem;          // [2][4096] shorts
    short* lB = (short*)smem + 8192;
    int kz = bid & 1, loc = bid >> 1;
    int xcd = loc & 7, l = loc >> 3;
    int mb = (xcd << 4) | (l >> 3), nb = l & 7;   // XCD band: A-chunk L2-resident
    const int m0 = mb * 64, n0 = nb * 64;
    const int wid = tid >> 6, lane = tid & 63;
    const int wr = wid >> 1, wc = wid & 1;
    const int fr = lane & 15, g = lane >> 4;

    const int srow = tid >> 3, c = tid & 7;       // coalesced: 8 lanes = 128B run
    const float* gA0 = A + (size_t)(m0 + srow) * IN_F + kz * 256 + c * 4;
    const float* gA1 = gA0 + 32 * IN_F;
    const short* gB0 = B3t + (size_t)(n0 + srow) * KP2 + kz * 512 + c * 8;
    const short* gB1 = gB0 + 32 * KP2;
    const int w0 = c * 512 + (((srow & ~7) | ((srow & 7) ^ c))) * 8;  // swizzled cell
    const int w1 = w0 + 256;                      // srow+32: same low bits

    f32x4 acc[2][2] = {};

    auto loadR = [&](SReg2& s, int t) {
      s.a0 = *reinterpret_cast<const float4*>(gA0 + t * 32);
      s.a1 = *reinterpret_cast<const float4*>(gA1 + t * 32);
      s.b0 = *reinterpret_cast<const int4*>(gB0 + t * 64);
      s.b1 = *reinterpret_cast<const int4*>(gB1 + t * 64);
    };
    auto cvt4 = [](float4 p) -> int4 {  // 4 f32 -> [ah,al] x4 packed dwords
      float xs[4] = {p.x, p.y, p.z, p.w};
      int out[4];
#pragma unroll
      for (int e = 0; e < 4; ++e) {
        _Float16 h = (_Float16)xs[e];
        _Float16 lo = (_Float16)(xs[e] - (float)h);
        unsigned short uh = __builtin_bit_cast(unsigned short, h);
        unsigned short ul = __builtin_bit_cast(unsigned short, lo);
        out[e] = (int)uh | ((int)ul << 16);
      }
      int4 r; r.x = out[0]; r.y = out[1]; r.z = out[2]; r.w = out[3];
      return r;
    };
    auto writeL = [&](int buf, SReg2& s) {
      *reinterpret_cast<int4*>(&lA[buf * 4096 + w0]) = cvt4(s.a0);
      *reinterpret_cast<int4*>(&lA[buf * 4096 + w1]) = cvt4(s.a1);
      *reinterpret_cast<int4*>(&lB[buf * 4096 + w0]) = s.b0;
      *reinterpret_cast<int4*>(&lB[buf * 4096 + w1]) = s.b1;
    };
    auto compute = [&](int buf) {
#pragma unroll
      for (int ks = 0; ks < 2; ++ks) {
        int s = ks * 4 + g;
        f16x8 af[2], bv[2];
#pragma unroll
        for (int m = 0; m < 2; ++m) {
          int row = wr * 32 + m * 16 + fr;
          int rs = (row & ~7) | ((row & 7) ^ s);
          af[m] = *reinterpret_cast<const f16x8*>(&lA[buf * 4096 + s * 512 + rs * 8]);
        }
#pragma unroll
        for (int n = 0; n < 2; ++n) {
          int row = wc * 32 + n * 16 + fr;
          int rs = (row & ~7) | ((row & 7) ^ s);
          bv[n] = *reinterpret_cast<const f16x8*>(&lB[buf * 4096 + s * 512 + rs * 8]);
        }
#pragma unroll
        for (int m = 0; m < 2; ++m)
#pragma unroll
          for (int n = 0; n < 2; ++n)
            acc[m][n] = __builtin_amdgcn_mfma_f32_16x16x32_f16(af[m], bv[n], acc[m][n], 0, 0, 0);
      }
    };

    SReg2 SA, SB;
    loadR(SA, 0); loadR(SB, 1);
    writeL(0, SA);
    loadR(SA, 2);
    __syncthreads();
    for (int t = 0; t < 4; t += 2) {
      writeL(1, SB); loadR(SB, t + 3);
      compute(0); __syncthreads();
      writeL(0, SA); loadR(SA, t + 4);
      compute(1); __syncthreads();
    }
    writeL(1, SB); loadR(SB, 7);
    compute(0); __syncthreads();
    writeL(0, SA);
    compute(1); __syncthreads();
    writeL(1, SB);
    compute(0); __syncthreads();
    compute(1);

#pragma unroll
    for (int m = 0; m < 2; ++m)
#pragma unroll
      for (int n = 0; n < 2; ++n) {
        int row = m0 + wr * 32 + m * 16 + g * 4;   // C/D: row=(lane>>4)*4+reg
        int col = n0 + wc * 32 + n * 16 + fr;      //      col=lane&15
#pragma unroll
        for (int r = 0; r < 4; ++r)
          atomicAdd(&Wh[(size_t)(row + r) * OUT_F + col], acc[m][n][r]);
      }
  } else {
    // ---- rank-by-counting; LDS staged with rotation swizzle (part p shifted 4p floats) ----
    float* ls = (float*)smem;   // 8192 floats
    for (int q = tid; q < 2048; q += 256) {
      float4 v = reinterpret_cast<const float4*>(s2)[q];
      int p = q >> 8, idx = (q & 255) * 4;
      *reinterpret_cast<float4*>(&ls[p * 1024 + ((idx + 4 * p) & 1023)]) = v;
    }
    __syncthreads();
    int rb = bid - 2048;
    int ki = rb * 32 + (tid >> 3);
    int part = tid & 7;
    int kp = ki >> 10, kidx = ki & 1023;
    float key = ls[kp * 1024 + ((kidx + 4 * kp) & 1023)];
    int rank = 0;
    int jbase = part * 1024;
#pragma unroll 4
    for (int q = 0; q < 256; ++q) {
      int idx = q * 4;
      float4 v = *reinterpret_cast<const float4*>(&ls[part * 1024 + ((idx + 4 * part) & 1023)]);
      int j = jbase + idx;
      rank += (v.x < key) || (v.x == key && (j + 0) < ki);
      rank += (v.y < key) || (v.y == key && (j + 1) < ki);
      rank += (v.z < key) || (v.z == key && (j + 2) < ki);
      rank += (v.w < key) || (v.w == key && (j + 3) < ki);
    }
    rank += __shfl_xor(rank, 1);
    rank += __shfl_xor(rank, 2);
    rank += __shfl_xor(rank, 4);
    if (part == 0) {
      s2s[rank] = key; perm[rank] = ki;
      eaA[rank] = expf(key); ebA[rank] = expf(LRALPHA * key);
    }
  }
}

// ---- passA: chunk sums [chunk][col] (+ block (NCH,0): scalar scans) ----
__global__ __launch_bounds__(256) void k_passA(const float* __restrict__ Wh,
                                               const float* __restrict__ eaA,
                                               const float* __restrict__ ebA,
                                               const int* __restrict__ perm,
                                               float* __restrict__ chunkA, float* __restrict__ chunkB,
                                               float* __restrict__ sufa, float* __restrict__ preb) {
  int t = threadIdx.x;
  if (blockIdx.x == NCH) {
    if (blockIdx.y != 0) return;
    // scalar scans: preb = excl-prefix(ebA), sufa = incl-suffix(eaA). 256 thr x 32.
    int lane = t & 63, w = t >> 6;
    float sa = 0.f, sb = 0.f;
#pragma unroll
    for (int q = 0; q < 8; ++q) {
      float4 va = reinterpret_cast<const float4*>(eaA)[t * 8 + q];
      float4 vb = reinterpret_cast<const float4*>(ebA)[t * 8 + q];
      sa += va.x + va.y + va.z + va.w;
      sb += vb.x + vb.y + vb.z + vb.w;
    }
    float pb = sb;
#pragma unroll
    for (int off = 1; off < 64; off <<= 1) { float v = __shfl_up(pb, off); if (lane >= off) pb += v; }
    float pa = sa;
#pragma unroll
    for (int off = 1; off < 64; off <<= 1) { float v = __shfl_down(pa, off); if (lane < 64 - off) pa += v; }
    __shared__ float wtb[4], wta[4];
    if (lane == 63) wtb[w] = pb;
    if (lane == 0)  wta[w] = pa;
    __syncthreads();
    if (t == 0) {
      float rb = 0.f;
      for (int i = 0; i < 4; ++i) { float tmp = wtb[i]; wtb[i] = rb; rb += tmp; }
      float ra = 0.f;
      for (int i = 3; i >= 0; --i) { float tmp = wta[i]; wta[i] = ra; ra += tmp; }
    }
    __syncthreads();
    float run = wtb[w] + (pb - sb);           // global exclusive prefix base
#pragma unroll
    for (int q = 0; q < 8; ++q) {
      float4 vb = reinterpret_cast<const float4*>(ebA)[t * 8 + q];
      float e4[4] = {vb.x, vb.y, vb.z, vb.w};
#pragma unroll
      for (int e = 0; e < 4; ++e) { preb[t * 32 + q * 4 + e] = run; run += e4[e]; }
    }
    if (t == 255) preb[NR] = run;
    run = wta[w] + (pa - sa);                 // global exclusive suffix base
#pragma unroll
    for (int q = 7; q >= 0; --q) {
      float4 va = reinterpret_cast<const float4*>(eaA)[t * 8 + q];
      float e4[4] = {va.x, va.y, va.z, va.w};
#pragma unroll
      for (int e = 3; e >= 0; --e) { run += e4[e]; sufa[t * 32 + q * 4 + e] = run; }
    }
    if (t == 0) sufa[NR] = 0.f;
    return;
  }
  int chunk = blockIdx.x;
  int col = blockIdx.y * 256 + t;
  float accA = 0.f, accB = 0.f;
  int r0 = chunk * CHR;
  for (int rl = 0; rl < CHR; ++rl) {
    int r = r0 + rl;
    float v = Wh[(size_t)perm[r] * OUT_F + col];
    accA += eaA[r] * v;
    accB += ebA[r] * v;
  }
  chunkA[chunk * OUT_F + col] = accA;
  chunkB[chunk * OUT_F + col] = accB;
}

// ---- passC: self-base (coalesced L2 reads of chunk sums) + per-row scans ----
__global__ __launch_bounds__(256) void k_passC(const float* __restrict__ Wh,
                                               const float* __restrict__ eaA,
                                               const float* __restrict__ ebA,
                                               const int* __restrict__ perm,
                                               const float* __restrict__ chunkA,
                                               const float* __restrict__ chunkB,
                                               float* __restrict__ SufA, float* __restrict__ PreB) {
  int chunk = blockIdx.x;
  int col = blockIdx.y * 256 + threadIdx.x;
  float bA = 0.f, bB = 0.f;
  for (int cp = chunk + 1; cp < NCH; ++cp) bA += chunkA[cp * OUT_F + col];
  for (int cp = 0; cp < chunk; ++cp) bB += chunkB[cp * OUT_F + col];
  int r0 = chunk * CHR;
  float acc = 0.f;
  for (int rl = CHR - 1; rl >= 0; --rl) {   // suffix incl.
    int r = r0 + rl;
    float v = Wh[(size_t)perm[r] * OUT_F + col];
    acc += eaA[r] * v;
    SufA[(size_t)r * OUT_F + col] = acc + bA;
  }
  acc = 0.f;
  for (int rl = 0; rl < CHR; ++rl) {        // prefix excl.
    int r = r0 + rl;
    float v = Wh[(size_t)perm[r] * OUT_F + col];
    PreB[(size_t)r * OUT_F + col] = acc + bB;
    acc += ebA[r] * v;
  }
  if (chunk == NCH - 1) {
    SufA[(size_t)NR * OUT_F + col] = 0.f;
    PreB[(size_t)NR * OUT_F + col] = acc + bB;
  }
}

// ---- per-row: binary search threshold rank, combine, elu ----
__global__ __launch_bounds__(256) void k_final(const float* __restrict__ s1,
                                               const float* __restrict__ s2s,
                                               const float* __restrict__ sufa,
                                               const float* __restrict__ preb,
                                               const float* __restrict__ SufA,
                                               const float* __restrict__ PreB,
                                               float* __restrict__ out) {
  int row = blockIdx.x * 4 + (threadIdx.x >> 6);
  int lane = threadIdx.x & 63;
  float sv = s1[row];
  float t = -sv;
  int lo = 0, hi = NR;
  while (lo < hi) {  // first index with s2s[idx] > t
    int mid = (lo + hi) >> 1;
    if (s2s[mid] > t) hi = mid; else lo = mid + 1;
  }
  float E1 = expf(sv), E1a = expf(LRALPHA * sv);
  float Z = E1 * sufa[lo] + E1a * preb[lo];
  const float* rA = SufA + (size_t)lo * OUT_F;
  const float* rB = PreB + (size_t)lo * OUT_F;
#pragma unroll
  for (int e = 0; e < 8; ++e) {
    int kc = e * 64 + lane;
    float num = E1 * rA[kc] + E1a * rB[kc];
    float h = num / Z;
    out[(size_t)row * OUT_F + kc] = (h > 0.f) ? h : expm1f(h);
  }
}

extern "C" void kernel_launch(void* const* d_in, const int* in_sizes, int n_in,
                              void* d_out, int out_size, void* d_ws, size_t ws_size,
                              hipStream_t stream) {
  (void)in_sizes; (void)n_in; (void)out_size; (void)ws_size;
  const float* feat_edge   = (const float*)d_in[0];
  const float* feat_edge_a = (const float*)d_in[1];
  const float* feat_node_a = (const float*)d_in[2];
  const float* weight      = (const float*)d_in[3];
  const float* att         = (const float*)d_in[4];
  float* out = (float*)d_out;

  char* ws = (char*)d_ws;
  size_t off = 0;
  auto alloc = [&](size_t bytes) { size_t o = off; off += (bytes + 255) & ~(size_t)255; return o; };

  float* Wh = (float*)(ws + alloc((size_t)NR * OUT_F * 4));           // 16.78 MB
  // Region hosts B3t (GEMM phase), then SufA+PreB (scan phase) — disjoint lifetimes.
  size_t regionOff = alloc((size_t)(NR + 1) * OUT_F * 4 * 2);          // 33.56 MB
  float* SufA = (float*)(ws + regionOff);
  float* PreB = (float*)(ws + regionOff + (size_t)(NR + 1) * OUT_F * 4);
  short* B3t  = (short*)(ws + regionOff);                              // 1.05 MB

  float* s1   = (float*)(ws + alloc(NR * 4));
  float* s2   = (float*)(ws + alloc(NR * 4));
  float* s2s  = (float*)(ws + alloc(NR * 4));
  int*   perm = (int*)  (ws + alloc(NR * 4));
  float* sufa = (float*)(ws + alloc((NR + 1) * 4));
  float* preb = (float*)(ws + alloc((NR + 1) * 4));
  float* eaA  = (float*)(ws + alloc(NR * 4));
  float* ebA  = (float*)(ws + alloc(NR * 4));
  float* chA  = (float*)(ws + alloc(NCH * OUT_F * 4));
  float* chB  = (float*)(ws + alloc(NCH * OUT_F * 4));

  k_prep<<<5632, 256, 0, stream>>>(feat_edge, feat_edge_a, att, weight, s1, s2, B3t, Wh);
  k_gemmrank<<<2304, 256, 0, stream>>>(feat_node_a, B3t, Wh, s2, s2s, perm, eaA, ebA);
  k_passA<<<dim3(NCH + 1, 2), 256, 0, stream>>>(Wh, eaA, ebA, perm, chA, chB, sufa, preb);
  k_passC<<<dim3(NCH, 2), 256, 0, stream>>>(Wh, eaA, ebA, perm, chA, chB, SufA, PreB);
  k_final<<<NR / 4, 256, 0, stream>>>(s1, s2s, sufa, preb, SufA, PreB, out);
}

// Round 12
// 139.944 us; speedup vs baseline: 1.2882x; 1.2882x over previous
//
#include <hip/hip_runtime.h>
#include <cstdint>
#include <cstddef>

#define LRALPHA 0.1f
static constexpr int NR = 8192;      // N and Na
static constexpr int EF = 256;
static constexpr int IN_F = 512;
static constexpr int OUT_F = 512;
static constexpr int KP2 = 1024;     // fp16 split-2, k'-interleaved [ah,al]
static constexpr int NCH = 128;      // chunks for column scans
static constexpr int CHR = 64;       // rows per chunk (NCH*CHR = 8192)

typedef __attribute__((ext_vector_type(8))) _Float16 f16x8;
typedef __attribute__((ext_vector_type(4))) float f32x4;

// ---- fused prep: s1/s2 dots (blocks 0..4095) + B pack ----
__global__ __launch_bounds__(256) void k_prep(const float* __restrict__ feat_edge,
                                              const float* __restrict__ feat_edge_a,
                                              const float* __restrict__ att,
                                              const float* __restrict__ W,
                                              float* __restrict__ s1,
                                              float* __restrict__ s2,
                                              short* __restrict__ B3t) {
  int b = blockIdx.x;
  if (b < 4096) {
    int vrow = b * 4 + (threadIdx.x >> 6);
    int lane = threadIdx.x & 63;
    const float* feat; const float* av; float* outp; int row;
    if (vrow < NR) { row = vrow; feat = feat_edge; av = att; outp = s1; }
    else { row = vrow - NR; feat = feat_edge_a; av = att + EF; outp = s2; }
    float4 f = reinterpret_cast<const float4*>(feat + (size_t)row * EF)[lane];
    float4 a = reinterpret_cast<const float4*>(av)[lane];
    float d = f.x * a.x + f.y * a.y + f.z * a.z + f.w * a.w;
#pragma unroll
    for (int off = 32; off > 0; off >>= 1) d += __shfl_xor(d, off);
    if (lane == 0) outp[row] = d;
  } else {
    int i = (b - 4096) * 256 + threadIdx.x;  // < 512*512
    int n = i >> 9, k = i & 511;
    float x = W[(size_t)k * OUT_F + n];
    _Float16 h = (_Float16)x;
    unsigned short u = __builtin_bit_cast(unsigned short, h);
    unsigned int w = (unsigned int)u | ((unsigned int)u << 16);
    *reinterpret_cast<unsigned int*>(B3t + (size_t)n * KP2 + 2 * k) = w;
  }
}

// ---- Wh = split2(A) @ B3t^T : 64x64 tile, BK'=128, 8 iters (HALVED barrier count) ----
// Cross-round finding: each __syncthreads-iteration costs ~740ns (vmcnt drain =
// full HBM latency, serial). So: fewer, fatter iterations. BK'=128 -> 8 barriers.
// XOR swizzle (row8 ^= slot&7) on LDS cells: conflict-reduced write AND read,
// global reads stay 64B-run coalesced. dbuf = 64KB -> 2 blocks/CU.
struct SReg4 { float4 a0, a1, a2, a3; int4 b0, b1, b2, b3; };

__device__ __forceinline__ int swz(int row, int slot) {
  return (row & ~7) | ((row & 7) ^ (slot & 7));
}

__global__ __launch_bounds__(256, 2) void k_gemm(const float* __restrict__ A,
                                                 const short* __restrict__ B3t,
                                                 float* __restrict__ Wh) {
  // per buffer: [slot=k'/8 (16)][row (64)][8 f16] = 16KB each for A,B
  __shared__ short lA[2][8192];
  __shared__ short lB[2][8192];
  const int tid = threadIdx.x;
  const int wid = tid >> 6, lane = tid & 63;
  const int wr = wid >> 1, wc = wid & 1;
  int bid = blockIdx.x;                       // 0..1023
  int xcd = bid & 7, loc = bid >> 3;
  int mb = (xcd << 4) | (loc >> 3), nb = loc & 7;   // XCD band: A-chunk L2-resident
  const int m0 = mb * 64, n0 = nb * 64;
  const int fr = lane & 15, g = lane >> 4;

  // staging map: row = tid>>2, quarter q = tid&3 (4 lanes = 64B contiguous run)
  const int srow = tid >> 2, q = tid & 3;
  const float* gA = A + (size_t)(m0 + srow) * IN_F + q * 16;    // 16 f32 per iter
  const short* gB = B3t + (size_t)(n0 + srow) * KP2 + q * 32;   // 32 shorts per iter
  int wA[4], wB[4];
#pragma unroll
  for (int j = 0; j < 4; ++j) {
    int s = 4 * q + j;
    wA[j] = s * 512 + swz(srow, s) * 8;
    wB[j] = s * 512 + swz(srow, s) * 8;
  }

  f32x4 acc[2][2] = {};

  auto loadR = [&](SReg4& s, int t) {
    const float* pa = gA + t * 64;
    s.a0 = *reinterpret_cast<const float4*>(pa);
    s.a1 = *reinterpret_cast<const float4*>(pa + 4);
    s.a2 = *reinterpret_cast<const float4*>(pa + 8);
    s.a3 = *reinterpret_cast<const float4*>(pa + 12);
    const short* pb = gB + t * 128;
    s.b0 = *reinterpret_cast<const int4*>(pb);
    s.b1 = *reinterpret_cast<const int4*>(pb + 8);
    s.b2 = *reinterpret_cast<const int4*>(pb + 16);
    s.b3 = *reinterpret_cast<const int4*>(pb + 24);
  };

  auto cvt4 = [](float4 p) -> int4 {  // 4 f32 -> 4 dwords of [ah | al]
    float xs[4] = {p.x, p.y, p.z, p.w};
    int out[4];
#pragma unroll
    for (int e = 0; e < 4; ++e) {
      _Float16 h = (_Float16)xs[e];
      _Float16 l = (_Float16)(xs[e] - (float)h);
      unsigned short uh = __builtin_bit_cast(unsigned short, h);
      unsigned short ul = __builtin_bit_cast(unsigned short, l);
      out[e] = (int)uh | ((int)ul << 16);
    }
    int4 r; r.x = out[0]; r.y = out[1]; r.z = out[2]; r.w = out[3];
    return r;
  };

  auto writeL = [&](int buf, SReg4& s) {
    *reinterpret_cast<int4*>(&lA[buf][wA[0]]) = cvt4(s.a0);
    *reinterpret_cast<int4*>(&lA[buf][wA[1]]) = cvt4(s.a1);
    *reinterpret_cast<int4*>(&lA[buf][wA[2]]) = cvt4(s.a2);
    *reinterpret_cast<int4*>(&lA[buf][wA[3]]) = cvt4(s.a3);
    *reinterpret_cast<int4*>(&lB[buf][wB[0]]) = s.b0;
    *reinterpret_cast<int4*>(&lB[buf][wB[1]]) = s.b1;
    *reinterpret_cast<int4*>(&lB[buf][wB[2]]) = s.b2;
    *reinterpret_cast<int4*>(&lB[buf][wB[3]]) = s.b3;
  };

  auto compute = [&](int buf) {
#pragma unroll
    for (int ks = 0; ks < 4; ++ks) {
      int s = ks * 4 + g;
      f16x8 af[2], bv[2];
#pragma unroll
      for (int m = 0; m < 2; ++m) {
        int row = wr * 32 + m * 16 + fr;
        af[m] = *reinterpret_cast<const f16x8*>(&lA[buf][s * 512 + swz(row, s) * 8]);
      }
#pragma unroll
      for (int n = 0; n < 2; ++n) {
        int row = wc * 32 + n * 16 + fr;
        bv[n] = *reinterpret_cast<const f16x8*>(&lB[buf][s * 512 + swz(row, s) * 8]);
      }
#pragma unroll
      for (int m = 0; m < 2; ++m)
#pragma unroll
        for (int n = 0; n < 2; ++n)
          acc[m][n] = __builtin_amdgcn_mfma_f32_16x16x32_f16(af[m], bv[n], acc[m][n], 0, 0, 0);
    }
  };

  SReg4 SA, SB;
  loadR(SA, 0); loadR(SB, 1);
  writeL(0, SA);
  loadR(SA, 2);
  __syncthreads();

  for (int t = 0; t < 4; t += 2) {
    writeL(1, SB); loadR(SB, t + 3);
    compute(0); __syncthreads();
    writeL(0, SA); loadR(SA, t + 4);
    compute(1); __syncthreads();
  }
  writeL(1, SB); loadR(SB, 7);   // write tile 5, load tile 7
  compute(0); __syncthreads();   // compute tile 4
  writeL(0, SA);                 // write tile 6
  compute(1); __syncthreads();   // compute tile 5
  writeL(1, SB);                 // write tile 7
  compute(0); __syncthreads();   // compute tile 6
  compute(1);                    // compute tile 7

#pragma unroll
  for (int m = 0; m < 2; ++m) {
#pragma unroll
    for (int n = 0; n < 2; ++n) {
      int row = m0 + wr * 32 + m * 16 + g * 4;   // C/D: row=(lane>>4)*4+reg
      int col = n0 + wc * 32 + n * 16 + fr;      //      col=lane&15
#pragma unroll
      for (int r = 0; r < 4; ++r)
        Wh[(size_t)(row + r) * OUT_F + col] = acc[m][n][r];
    }
  }
}

// ---- rank-by-counting, LDS-staged (rotation swizzle), emits exp tables ----
__global__ __launch_bounds__(256) void k_rank(const float* __restrict__ s2,
                                              float* __restrict__ s2s, int* __restrict__ perm,
                                              float* __restrict__ eaA, float* __restrict__ ebA) {
  __shared__ float ls[8192];
  int t = threadIdx.x;
  for (int q = t; q < 2048; q += 256) {
    float4 v = reinterpret_cast<const float4*>(s2)[q];
    int p = q >> 8, idx = (q & 255) * 4;
    *reinterpret_cast<float4*>(&ls[p * 1024 + ((idx + 4 * p) & 1023)]) = v;
  }
  __syncthreads();

  int ki = blockIdx.x * 32 + (t >> 3);   // 256 blocks x 32 keys
  int part = t & 7;                      // 8 lanes share one key
  int kp = ki >> 10, kidx = ki & 1023;
  float key = ls[kp * 1024 + ((kidx + 4 * kp) & 1023)];
  int rank = 0;
  int jbase = part * 1024;
#pragma unroll 4
  for (int q = 0; q < 256; ++q) {
    int idx = q * 4;
    float4 v = *reinterpret_cast<const float4*>(&ls[part * 1024 + ((idx + 4 * part) & 1023)]);
    int j = jbase + idx;
    rank += (v.x < key) || (v.x == key && (j + 0) < ki);
    rank += (v.y < key) || (v.y == key && (j + 1) < ki);
    rank += (v.z < key) || (v.z == key && (j + 2) < ki);
    rank += (v.w < key) || (v.w == key && (j + 3) < ki);
  }
  rank += __shfl_xor(rank, 1);
  rank += __shfl_xor(rank, 2);
  rank += __shfl_xor(rank, 4);
  if (part == 0) {
    s2s[rank] = key; perm[rank] = ki;
    eaA[rank] = expf(key); ebA[rank] = expf(LRALPHA * key);
  }
}

// ---- scalar scans: preb = excl-prefix(ebA), sufa = incl-suffix(eaA); shfl-based ----
__global__ __launch_bounds__(1024) void k_scan(const float* __restrict__ eaA,
                                               const float* __restrict__ ebA,
                                               float* __restrict__ sufa,
                                               float* __restrict__ preb) {
  int t = threadIdx.x;
  int lane = t & 63, w = t >> 6;   // 16 waves
  float4 a0 = reinterpret_cast<const float4*>(eaA)[t * 2];
  float4 a1 = reinterpret_cast<const float4*>(eaA)[t * 2 + 1];
  float4 b0 = reinterpret_cast<const float4*>(ebA)[t * 2];
  float4 b1 = reinterpret_cast<const float4*>(ebA)[t * 2 + 1];
  float ea[8] = {a0.x, a0.y, a0.z, a0.w, a1.x, a1.y, a1.z, a1.w};
  float eb[8] = {b0.x, b0.y, b0.z, b0.w, b1.x, b1.y, b1.z, b1.w};
  float sa = 0.f, sb = 0.f;
#pragma unroll
  for (int e = 0; e < 8; ++e) { sa += ea[e]; sb += eb[e]; }

  float pb = sb;   // wave inclusive prefix
#pragma unroll
  for (int off = 1; off < 64; off <<= 1) { float v = __shfl_up(pb, off); if (lane >= off) pb += v; }
  float pa = sa;   // wave inclusive suffix
#pragma unroll
  for (int off = 1; off < 64; off <<= 1) { float v = __shfl_down(pa, off); if (lane < 64 - off) pa += v; }

  __shared__ float wtb[16], wta[16];
  if (lane == 63) wtb[w] = pb;
  if (lane == 0)  wta[w] = pa;
  __syncthreads();
  if (t == 0) {
    float rb = 0.f;
    for (int i = 0; i < 16; ++i) { float tmp = wtb[i]; wtb[i] = rb; rb += tmp; }
    float ra = 0.f;
    for (int i = 15; i >= 0; --i) { float tmp = wta[i]; wta[i] = ra; ra += tmp; }
  }
  __syncthreads();

  float run = wtb[w] + (pb - sb);         // exclusive prefix base
#pragma unroll
  for (int e = 0; e < 8; ++e) { preb[t * 8 + e] = run; run += eb[e]; }
  if (t == 1023) preb[NR] = run;
  run = wta[w] + (pa - sa);               // exclusive suffix base
#pragma unroll
  for (int e = 7; e >= 0; --e) { run += ea[e]; sufa[t * 8 + e] = run; }
  if (t == 0) sufa[NR] = 0.f;
}

// ---- passA: chunk sums -> transposed [col][chunk] for passB's coalesced scan ----
__global__ __launch_bounds__(256) void k_passA(const float* __restrict__ Wh,
                                               const float* __restrict__ eaA,
                                               const float* __restrict__ ebA,
                                               const int* __restrict__ perm,
                                               float* __restrict__ chunkA, float* __restrict__ chunkB) {
  int chunk = blockIdx.x;
  int col = blockIdx.y * 256 + threadIdx.x;
  float accA = 0.f, accB = 0.f;
  int r0 = chunk * CHR;
  for (int rl = 0; rl < CHR; ++rl) {
    int r = r0 + rl;
    float v = Wh[(size_t)perm[r] * OUT_F + col];
    accA += eaA[r] * v;
    accB += ebA[r] * v;
  }
  chunkA[(size_t)col * NCH + chunk] = accA;
  chunkB[(size_t)col * NCH + chunk] = accB;
}

// ---- passB: wave-per-column shfl scan of 128 chunk sums -> bases [c][col] ----
__global__ __launch_bounds__(256) void k_passB(const float* __restrict__ chunkA,
                                               const float* __restrict__ chunkB,
                                               float* __restrict__ baseA, float* __restrict__ baseB) {
  int lane = threadIdx.x & 63, w = threadIdx.x >> 6;
  int col = blockIdx.x * 4 + w;           // 128 blocks x 4 waves = 512 cols
  float xa0 = chunkA[(size_t)col * NCH + lane];
  float xa1 = chunkA[(size_t)col * NCH + 64 + lane];
  float yb0 = chunkB[(size_t)col * NCH + lane];
  float yb1 = chunkB[(size_t)col * NCH + 64 + lane];

  float p0 = yb0, p1 = yb1;
#pragma unroll
  for (int off = 1; off < 64; off <<= 1) {
    float v0 = __shfl_up(p0, off); if (lane >= off) p0 += v0;
    float v1 = __shfl_up(p1, off); if (lane >= off) p1 += v1;
  }
  float T0 = __shfl(p0, 63);
  p1 += T0;
  baseB[(size_t)lane * OUT_F + col] = p0 - yb0;
  baseB[(size_t)(64 + lane) * OUT_F + col] = p1 - yb1;

  float s0 = xa0, s1 = xa1;
#pragma unroll
  for (int off = 1; off < 64; off <<= 1) {
    float v1 = __shfl_down(s1, off); if (lane < 64 - off) s1 += v1;
    float v0 = __shfl_down(s0, off); if (lane < 64 - off) s0 += v0;
  }
  float S1 = __shfl(s1, 0);
  s0 += S1;
  baseA[(size_t)lane * OUT_F + col] = s0 - xa0;
  baseA[(size_t)(64 + lane) * OUT_F + col] = s1 - xa1;
}

__global__ __launch_bounds__(256) void k_passC(const float* __restrict__ Wh,
                                               const float* __restrict__ eaA,
                                               const float* __restrict__ ebA,
                                               const int* __restrict__ perm,
                                               const float* __restrict__ baseA,
                                               const float* __restrict__ baseB,
                                               float* __restrict__ SufA, float* __restrict__ PreB) {
  int chunk = blockIdx.x;
  int col = blockIdx.y * 256 + threadIdx.x;
  int r0 = chunk * CHR;
  float bA = baseA[(size_t)chunk * OUT_F + col];
  float bB = baseB[(size_t)chunk * OUT_F + col];
  float acc = 0.f;
  for (int rl = CHR - 1; rl >= 0; --rl) {   // suffix incl.
    int r = r0 + rl;
    float v = Wh[(size_t)perm[r] * OUT_F + col];
    acc += eaA[r] * v;
    SufA[(size_t)r * OUT_F + col] = acc + bA;
  }
  acc = 0.f;
  for (int rl = 0; rl < CHR; ++rl) {        // prefix excl.
    int r = r0 + rl;
    float v = Wh[(size_t)perm[r] * OUT_F + col];
    PreB[(size_t)r * OUT_F + col] = acc + bB;
    acc += ebA[r] * v;
  }
  if (chunk == NCH - 1) {
    SufA[(size_t)NR * OUT_F + col] = 0.f;
    PreB[(size_t)NR * OUT_F + col] = acc + bB;
  }
}

// ---- per-row: binary search threshold rank, combine, elu ----
__global__ __launch_bounds__(256) void k_final(const float* __restrict__ s1,
                                               const float* __restrict__ s2s,
                                               const float* __restrict__ sufa,
                                               const float* __restrict__ preb,
                                               const float* __restrict__ SufA,
                                               const float* __restrict__ PreB,
                                               float* __restrict__ out) {
  int row = blockIdx.x * 4 + (threadIdx.x >> 6);
  int lane = threadIdx.x & 63;
  float sv = s1[row];
  float t = -sv;
  int lo = 0, hi = NR;
  while (lo < hi) {  // first index with s2s[idx] > t
    int mid = (lo + hi) >> 1;
    if (s2s[mid] > t) hi = mid; else lo = mid + 1;
  }
  float E1 = expf(sv), E1a = expf(LRALPHA * sv);
  float Z = E1 * sufa[lo] + E1a * preb[lo];
  const float* rA = SufA + (size_t)lo * OUT_F;
  const float* rB = PreB + (size_t)lo * OUT_F;
#pragma unroll
  for (int e = 0; e < 8; ++e) {
    int kc = e * 64 + lane;
    float num = E1 * rA[kc] + E1a * rB[kc];
    float h = num / Z;
    out[(size_t)row * OUT_F + kc] = (h > 0.f) ? h : expm1f(h);
  }
}

extern "C" void kernel_launch(void* const* d_in, const int* in_sizes, int n_in,
                              void* d_out, int out_size, void* d_ws, size_t ws_size,
                              hipStream_t stream) {
  (void)in_sizes; (void)n_in; (void)out_size; (void)ws_size;
  const float* feat_edge   = (const float*)d_in[0];
  const float* feat_edge_a = (const float*)d_in[1];
  const float* feat_node_a = (const float*)d_in[2];
  const float* weight      = (const float*)d_in[3];
  const float* att         = (const float*)d_in[4];
  float* out = (float*)d_out;

  char* ws = (char*)d_ws;
  size_t off = 0;
  auto alloc = [&](size_t bytes) { size_t o = off; off += (bytes + 255) & ~(size_t)255; return o; };

  float* Wh = (float*)(ws + alloc((size_t)NR * OUT_F * 4));           // 16.78 MB
  size_t regionOff = alloc((size_t)(NR + 1) * OUT_F * 4 * 2);          // 33.56 MB
  float* SufA = (float*)(ws + regionOff);
  float* PreB = (float*)(ws + regionOff + (size_t)(NR + 1) * OUT_F * 4);
  short* B3t  = (short*)(ws + regionOff);                              // 1.05 MB

  float* s1   = (float*)(ws + alloc(NR * 4));
  float* s2   = (float*)(ws + alloc(NR * 4));
  float* s2s  = (float*)(ws + alloc(NR * 4));
  int*   perm = (int*)  (ws + alloc(NR * 4));
  float* sufa = (float*)(ws + alloc((NR + 1) * 4));
  float* preb = (float*)(ws + alloc((NR + 1) * 4));
  float* eaA  = (float*)(ws + alloc(NR * 4));
  float* ebA  = (float*)(ws + alloc(NR * 4));
  float* chA  = (float*)(ws + alloc(NCH * OUT_F * 4));
  float* chB  = (float*)(ws + alloc(NCH * OUT_F * 4));
  float* bsA  = (float*)(ws + alloc(NCH * OUT_F * 4));
  float* bsB  = (float*)(ws + alloc(NCH * OUT_F * 4));

  k_prep<<<4096 + 1024, 256, 0, stream>>>(feat_edge, feat_edge_a, att, weight, s1, s2, B3t);
  k_gemm<<<1024, 256, 0, stream>>>(feat_node_a, B3t, Wh);
  k_rank<<<NR / 32, 256, 0, stream>>>(s2, s2s, perm, eaA, ebA);
  k_scan<<<1, 1024, 0, stream>>>(eaA, ebA, sufa, preb);
  k_passA<<<dim3(NCH, 2), 256, 0, stream>>>(Wh, eaA, ebA, perm, chA, chB);
  k_passB<<<NCH, 256, 0, stream>>>(chA, chB, bsA, bsB);
  k_passC<<<dim3(NCH, 2), 256, 0, stream>>>(Wh, eaA, ebA, perm, bsA, bsB, SufA, PreB);
  k_final<<<NR / 4, 256, 0, stream>>>(s1, s2s, sufa, preb, SufA, PreB, out);
}

// Round 14
// 86.299 us; speedup vs baseline: 2.0890x; 1.6216x over previous
//
#include <hip/hip_runtime.h>
#include <cstdint>
#include <cstddef>

#define LRALPHA 0.1f
static constexpr int NR = 8192;      // N and Na
static constexpr int EF = 256;
static constexpr int IN_F = 512;
static constexpr int OUT_F = 512;
static constexpr int KP2 = 1024;     // fp16 split-2, k'-interleaved [ah,al]
static constexpr int NCH = 128;      // chunks for column scans
static constexpr int CHR = 64;       // rows per chunk (NCH*CHR = 8192)

typedef __attribute__((ext_vector_type(8))) _Float16 f16x8;
typedef __attribute__((ext_vector_type(4))) float f32x4;

// ---- fused prep: s1/s2 dots (blocks 0..4095) + B pack ----
__global__ __launch_bounds__(256) void k_prep(const float* __restrict__ feat_edge,
                                              const float* __restrict__ feat_edge_a,
                                              const float* __restrict__ att,
                                              const float* __restrict__ W,
                                              float* __restrict__ s1,
                                              float* __restrict__ s2,
                                              short* __restrict__ B3t) {
  int b = blockIdx.x;
  if (b < 4096) {
    int vrow = b * 4 + (threadIdx.x >> 6);
    int lane = threadIdx.x & 63;
    const float* feat; const float* av; float* outp; int row;
    if (vrow < NR) { row = vrow; feat = feat_edge; av = att; outp = s1; }
    else { row = vrow - NR; feat = feat_edge_a; av = att + EF; outp = s2; }
    float4 f = reinterpret_cast<const float4*>(feat + (size_t)row * EF)[lane];
    float4 a = reinterpret_cast<const float4*>(av)[lane];
    float d = f.x * a.x + f.y * a.y + f.z * a.z + f.w * a.w;
#pragma unroll
    for (int off = 32; off > 0; off >>= 1) d += __shfl_xor(d, off);
    if (lane == 0) outp[row] = d;
  } else {
    int i = (b - 4096) * 256 + threadIdx.x;  // < 512*512
    int n = i >> 9, k = i & 511;
    float x = W[(size_t)k * OUT_F + n];
    _Float16 h = (_Float16)x;
    unsigned short u = __builtin_bit_cast(unsigned short, h);
    unsigned int w = (unsigned int)u | ((unsigned int)u << 16);
    *reinterpret_cast<unsigned int*>(B3t + (size_t)n * KP2 + 2 * k) = w;
  }
}

// ---- Wh = split2(A) @ B3t^T : 64x64 tile, BK'=128, 8 iters (R12, kept) ----
struct SReg4 { float4 a0, a1, a2, a3; int4 b0, b1, b2, b3; };

__device__ __forceinline__ int swz(int row, int slot) {
  return (row & ~7) | ((row & 7) ^ (slot & 7));
}

__global__ __launch_bounds__(256, 2) void k_gemm(const float* __restrict__ A,
                                                 const short* __restrict__ B3t,
                                                 float* __restrict__ Wh) {
  __shared__ short lA[2][8192];
  __shared__ short lB[2][8192];
  const int tid = threadIdx.x;
  const int wid = tid >> 6, lane = tid & 63;
  const int wr = wid >> 1, wc = wid & 1;
  int bid = blockIdx.x;                       // 0..1023
  int xcd = bid & 7, loc = bid >> 3;
  int mb = (xcd << 4) | (loc >> 3), nb = loc & 7;   // XCD band: A-chunk L2-resident
  const int m0 = mb * 64, n0 = nb * 64;
  const int fr = lane & 15, g = lane >> 4;

  const int srow = tid >> 2, q = tid & 3;
  const float* gA = A + (size_t)(m0 + srow) * IN_F + q * 16;
  const short* gB = B3t + (size_t)(n0 + srow) * KP2 + q * 32;
  int wA[4], wB[4];
#pragma unroll
  for (int j = 0; j < 4; ++j) {
    int s = 4 * q + j;
    wA[j] = s * 512 + swz(srow, s) * 8;
    wB[j] = s * 512 + swz(srow, s) * 8;
  }

  f32x4 acc[2][2] = {};

  auto loadR = [&](SReg4& s, int t) {
    const float* pa = gA + t * 64;
    s.a0 = *reinterpret_cast<const float4*>(pa);
    s.a1 = *reinterpret_cast<const float4*>(pa + 4);
    s.a2 = *reinterpret_cast<const float4*>(pa + 8);
    s.a3 = *reinterpret_cast<const float4*>(pa + 12);
    const short* pb = gB + t * 128;
    s.b0 = *reinterpret_cast<const int4*>(pb);
    s.b1 = *reinterpret_cast<const int4*>(pb + 8);
    s.b2 = *reinterpret_cast<const int4*>(pb + 16);
    s.b3 = *reinterpret_cast<const int4*>(pb + 24);
  };

  auto cvt4 = [](float4 p) -> int4 {
    float xs[4] = {p.x, p.y, p.z, p.w};
    int out[4];
#pragma unroll
    for (int e = 0; e < 4; ++e) {
      _Float16 h = (_Float16)xs[e];
      _Float16 l = (_Float16)(xs[e] - (float)h);
      unsigned short uh = __builtin_bit_cast(unsigned short, h);
      unsigned short ul = __builtin_bit_cast(unsigned short, l);
      out[e] = (int)uh | ((int)ul << 16);
    }
    int4 r; r.x = out[0]; r.y = out[1]; r.z = out[2]; r.w = out[3];
    return r;
  };

  auto writeL = [&](int buf, SReg4& s) {
    *reinterpret_cast<int4*>(&lA[buf][wA[0]]) = cvt4(s.a0);
    *reinterpret_cast<int4*>(&lA[buf][wA[1]]) = cvt4(s.a1);
    *reinterpret_cast<int4*>(&lA[buf][wA[2]]) = cvt4(s.a2);
    *reinterpret_cast<int4*>(&lA[buf][wA[3]]) = cvt4(s.a3);
    *reinterpret_cast<int4*>(&lB[buf][wB[0]]) = s.b0;
    *reinterpret_cast<int4*>(&lB[buf][wB[1]]) = s.b1;
    *reinterpret_cast<int4*>(&lB[buf][wB[2]]) = s.b2;
    *reinterpret_cast<int4*>(&lB[buf][wB[3]]) = s.b3;
  };

  auto compute = [&](int buf) {
#pragma unroll
    for (int ks = 0; ks < 4; ++ks) {
      int s = ks * 4 + g;
      f16x8 af[2], bv[2];
#pragma unroll
      for (int m = 0; m < 2; ++m) {
        int row = wr * 32 + m * 16 + fr;
        af[m] = *reinterpret_cast<const f16x8*>(&lA[buf][s * 512 + swz(row, s) * 8]);
      }
#pragma unroll
      for (int n = 0; n < 2; ++n) {
        int row = wc * 32 + n * 16 + fr;
        bv[n] = *reinterpret_cast<const f16x8*>(&lB[buf][s * 512 + swz(row, s) * 8]);
      }
#pragma unroll
      for (int m = 0; m < 2; ++m)
#pragma unroll
        for (int n = 0; n < 2; ++n)
          acc[m][n] = __builtin_amdgcn_mfma_f32_16x16x32_f16(af[m], bv[n], acc[m][n], 0, 0, 0);
    }
  };

  SReg4 SA, SB;
  loadR(SA, 0); loadR(SB, 1);
  writeL(0, SA);
  loadR(SA, 2);
  __syncthreads();

  for (int t = 0; t < 4; t += 2) {
    writeL(1, SB); loadR(SB, t + 3);
    compute(0); __syncthreads();
    writeL(0, SA); loadR(SA, t + 4);
    compute(1); __syncthreads();
  }
  writeL(1, SB); loadR(SB, 7);
  compute(0); __syncthreads();
  writeL(0, SA);
  compute(1); __syncthreads();
  writeL(1, SB);
  compute(0); __syncthreads();
  compute(1);

#pragma unroll
  for (int m = 0; m < 2; ++m) {
#pragma unroll
    for (int n = 0; n < 2; ++n) {
      int row = m0 + wr * 32 + m * 16 + g * 4;   // C/D: row=(lane>>4)*4+reg
      int col = n0 + wc * 32 + n * 16 + fr;      //      col=lane&15
#pragma unroll
      for (int r = 0; r < 4; ++r)
        Wh[(size_t)(row + r) * OUT_F + col] = acc[m][n][r];
    }
  }
}

// ---- rank: 32 lanes/key, 1024 blocks (4/CU), aligned padded LDS,
//      UNSIGNED-monotone key transform (R13 bug: compared as signed) ----
__global__ __launch_bounds__(256) void k_rank(const float* __restrict__ s2,
                                              float* __restrict__ s2s, int* __restrict__ perm,
                                              float* __restrict__ eaA, float* __restrict__ ebA) {
  __shared__ unsigned int ls[32 * 260];  // part p at ls[p*260+i]; addr 4*(65p+q) -> b128 ok
  int t = threadIdx.x;
#pragma unroll
  for (int k = 0; k < 8; ++k) {
    int q = t + 256 * k;                  // float4 index 0..2047
    int p = q >> 6, i = q & 63;
    uint4 u = reinterpret_cast<const uint4*>(s2)[q];
    uint4 v;
    v.x = (u.x >> 31) ? ~u.x : (u.x | 0x80000000u);
    v.y = (u.y >> 31) ? ~u.y : (u.y | 0x80000000u);
    v.z = (u.z >> 31) ? ~u.z : (u.z | 0x80000000u);
    v.w = (u.w >> 31) ? ~u.w : (u.w | 0x80000000u);
    *reinterpret_cast<uint4*>(&ls[p * 260 + i * 4]) = v;
  }
  __syncthreads();

  int ki = blockIdx.x * 8 + (t >> 5);    // 1024 blocks x 8 keys
  int part = t & 31;                     // 32 lanes share one key
  unsigned int key = ls[(ki >> 8) * 260 + (ki & 255)];
  int rank = 0;
  const int base = part * 260;
  int jbase = part * 256;
#pragma unroll 8
  for (int q = 0; q < 64; ++q) {
    uint4 v = *reinterpret_cast<const uint4*>(&ls[base + q * 4]);
    int j = jbase + q * 4;
    rank += (v.x < key) || (v.x == key && (j + 0) < ki);
    rank += (v.y < key) || (v.y == key && (j + 1) < ki);
    rank += (v.z < key) || (v.z == key && (j + 2) < ki);
    rank += (v.w < key) || (v.w == key && (j + 3) < ki);
  }
  rank += __shfl_xor(rank, 1);
  rank += __shfl_xor(rank, 2);
  rank += __shfl_xor(rank, 4);
  rank += __shfl_xor(rank, 8);
  rank += __shfl_xor(rank, 16);
  if (part == 0) {
    float kf = s2[ki];
    s2s[rank] = kf; perm[rank] = ki;
    eaA[rank] = expf(kf); ebA[rank] = expf(LRALPHA * kf);
  }
}

// ---- scalar scans: preb = excl-prefix(ebA), sufa = incl-suffix(eaA); shfl-based ----
__global__ __launch_bounds__(1024) void k_scan(const float* __restrict__ eaA,
                                               const float* __restrict__ ebA,
                                               float* __restrict__ sufa,
                                               float* __restrict__ preb) {
  int t = threadIdx.x;
  int lane = t & 63, w = t >> 6;   // 16 waves
  float4 a0 = reinterpret_cast<const float4*>(eaA)[t * 2];
  float4 a1 = reinterpret_cast<const float4*>(eaA)[t * 2 + 1];
  float4 b0 = reinterpret_cast<const float4*>(ebA)[t * 2];
  float4 b1 = reinterpret_cast<const float4*>(ebA)[t * 2 + 1];
  float ea[8] = {a0.x, a0.y, a0.z, a0.w, a1.x, a1.y, a1.z, a1.w};
  float eb[8] = {b0.x, b0.y, b0.z, b0.w, b1.x, b1.y, b1.z, b1.w};
  float sa = 0.f, sb = 0.f;
#pragma unroll
  for (int e = 0; e < 8; ++e) { sa += ea[e]; sb += eb[e]; }

  float pb = sb;
#pragma unroll
  for (int off = 1; off < 64; off <<= 1) { float v = __shfl_up(pb, off); if (lane >= off) pb += v; }
  float pa = sa;
#pragma unroll
  for (int off = 1; off < 64; off <<= 1) { float v = __shfl_down(pa, off); if (lane < 64 - off) pa += v; }

  __shared__ float wtb[16], wta[16];
  if (lane == 63) wtb[w] = pb;
  if (lane == 0)  wta[w] = pa;
  __syncthreads();
  if (t == 0) {
    float rb = 0.f;
    for (int i = 0; i < 16; ++i) { float tmp = wtb[i]; wtb[i] = rb; rb += tmp; }
    float ra = 0.f;
    for (int i = 15; i >= 0; --i) { float tmp = wta[i]; wta[i] = ra; ra += tmp; }
  }
  __syncthreads();

  float run = wtb[w] + (pb - sb);
#pragma unroll
  for (int e = 0; e < 8; ++e) { preb[t * 8 + e] = run; run += eb[e]; }
  if (t == 1023) preb[NR] = run;
  run = wta[w] + (pa - sa);
#pragma unroll
  for (int e = 7; e >= 0; --e) { run += ea[e]; sufa[t * 8 + e] = run; }
  if (t == 0) sufa[NR] = 0.f;
}

// ---- passA: chunk sums -> transposed [col][chunk] for passB's coalesced scan ----
__global__ __launch_bounds__(256) void k_passA(const float* __restrict__ Wh,
                                               const float* __restrict__ eaA,
                                               const float* __restrict__ ebA,
                                               const int* __restrict__ perm,
                                               float* __restrict__ chunkA, float* __restrict__ chunkB) {
  int chunk = blockIdx.x;
  int col = blockIdx.y * 256 + threadIdx.x;
  float accA = 0.f, accB = 0.f;
  int r0 = chunk * CHR;
  for (int rl = 0; rl < CHR; ++rl) {
    int r = r0 + rl;
    float v = Wh[(size_t)perm[r] * OUT_F + col];
    accA += eaA[r] * v;
    accB += ebA[r] * v;
  }
  chunkA[(size_t)col * NCH + chunk] = accA;
  chunkB[(size_t)col * NCH + chunk] = accB;
}

// ---- passB: wave-per-column shfl scan of 128 chunk sums -> bases [c][col] ----
__global__ __launch_bounds__(256) void k_passB(const float* __restrict__ chunkA,
                                               const float* __restrict__ chunkB,
                                               float* __restrict__ baseA, float* __restrict__ baseB) {
  int lane = threadIdx.x & 63, w = threadIdx.x >> 6;
  int col = blockIdx.x * 4 + w;           // 128 blocks x 4 waves = 512 cols
  float xa0 = chunkA[(size_t)col * NCH + lane];
  float xa1 = chunkA[(size_t)col * NCH + 64 + lane];
  float yb0 = chunkB[(size_t)col * NCH + lane];
  float yb1 = chunkB[(size_t)col * NCH + 64 + lane];

  float p0 = yb0, p1 = yb1;
#pragma unroll
  for (int off = 1; off < 64; off <<= 1) {
    float v0 = __shfl_up(p0, off); if (lane >= off) p0 += v0;
    float v1 = __shfl_up(p1, off); if (lane >= off) p1 += v1;
  }
  float T0 = __shfl(p0, 63);
  p1 += T0;
  baseB[(size_t)lane * OUT_F + col] = p0 - yb0;
  baseB[(size_t)(64 + lane) * OUT_F + col] = p1 - yb1;

  float s0 = xa0, s1 = xa1;
#pragma unroll
  for (int off = 1; off < 64; off <<= 1) {
    float v1 = __shfl_down(s1, off); if (lane < 64 - off) s1 += v1;
    float v0 = __shfl_down(s0, off); if (lane < 64 - off) s0 += v0;
  }
  float S1 = __shfl(s1, 0);
  s0 += S1;
  baseA[(size_t)lane * OUT_F + col] = s0 - xa0;
  baseA[(size_t)(64 + lane) * OUT_F + col] = s1 - xa1;
}

__global__ __launch_bounds__(256) void k_passC(const float* __restrict__ Wh,
                                               const float* __restrict__ eaA,
                                               const float* __restrict__ ebA,
                                               const int* __restrict__ perm,
                                               const float* __restrict__ baseA,
                                               const float* __restrict__ baseB,
                                               float* __restrict__ SufA, float* __restrict__ PreB) {
  int chunk = blockIdx.x;
  int col = blockIdx.y * 256 + threadIdx.x;
  int r0 = chunk * CHR;
  float bA = baseA[(size_t)chunk * OUT_F + col];
  float bB = baseB[(size_t)chunk * OUT_F + col];
  float acc = 0.f;
  for (int rl = CHR - 1; rl >= 0; --rl) {   // suffix incl.
    int r = r0 + rl;
    float v = Wh[(size_t)perm[r] * OUT_F + col];
    acc += eaA[r] * v;
    SufA[(size_t)r * OUT_F + col] = acc + bA;
  }
  acc = 0.f;
  for (int rl = 0; rl < CHR; ++rl) {        // prefix excl.
    int r = r0 + rl;
    float v = Wh[(size_t)perm[r] * OUT_F + col];
    PreB[(size_t)r * OUT_F + col] = acc + bB;
    acc += ebA[r] * v;
  }
  if (chunk == NCH - 1) {
    SufA[(size_t)NR * OUT_F + col] = 0.f;
    PreB[(size_t)NR * OUT_F + col] = acc + bB;
  }
}

// ---- per-row: binary search threshold rank, combine, elu ----
__global__ __launch_bounds__(256) void k_final(const float* __restrict__ s1,
                                               const float* __restrict__ s2s,
                                               const float* __restrict__ sufa,
                                               const float* __restrict__ preb,
                                               const float* __restrict__ SufA,
                                               const float* __restrict__ PreB,
                                               float* __restrict__ out) {
  int row = blockIdx.x * 4 + (threadIdx.x >> 6);
  int lane = threadIdx.x & 63;
  float sv = s1[row];
  float t = -sv;
  int lo = 0, hi = NR;
  while (lo < hi) {  // first index with s2s[idx] > t
    int mid = (lo + hi) >> 1;
    if (s2s[mid] > t) hi = mid; else lo = mid + 1;
  }
  float E1 = expf(sv), E1a = expf(LRALPHA * sv);
  float Z = E1 * sufa[lo] + E1a * preb[lo];
  const float* rA = SufA + (size_t)lo * OUT_F;
  const float* rB = PreB + (size_t)lo * OUT_F;
#pragma unroll
  for (int e = 0; e < 8; ++e) {
    int kc = e * 64 + lane;
    float num = E1 * rA[kc] + E1a * rB[kc];
    float h = num / Z;
    out[(size_t)row * OUT_F + kc] = (h > 0.f) ? h : expm1f(h);
  }
}

extern "C" void kernel_launch(void* const* d_in, const int* in_sizes, int n_in,
                              void* d_out, int out_size, void* d_ws, size_t ws_size,
                              hipStream_t stream) {
  (void)in_sizes; (void)n_in; (void)out_size; (void)ws_size;
  const float* feat_edge   = (const float*)d_in[0];
  const float* feat_edge_a = (const float*)d_in[1];
  const float* feat_node_a = (const float*)d_in[2];
  const float* weight      = (const float*)d_in[3];
  const float* att         = (const float*)d_in[4];
  float* out = (float*)d_out;

  char* ws = (char*)d_ws;
  size_t off = 0;
  auto alloc = [&](size_t bytes) { size_t o = off; off += (bytes + 255) & ~(size_t)255; return o; };

  float* Wh = (float*)(ws + alloc((size_t)NR * OUT_F * 4));           // 16.78 MB
  size_t regionOff = alloc((size_t)(NR + 1) * OUT_F * 4 * 2);          // 33.56 MB
  float* SufA = (float*)(ws + regionOff);
  float* PreB = (float*)(ws + regionOff + (size_t)(NR + 1) * OUT_F * 4);
  short* B3t  = (short*)(ws + regionOff);                              // 1.05 MB

  float* s1   = (float*)(ws + alloc(NR * 4));
  float* s2   = (float*)(ws + alloc(NR * 4));
  float* s2s  = (float*)(ws + alloc(NR * 4));
  int*   perm = (int*)  (ws + alloc(NR * 4));
  float* sufa = (float*)(ws + alloc((NR + 1) * 4));
  float* preb = (float*)(ws + alloc((NR + 1) * 4));
  float* eaA  = (float*)(ws + alloc(NR * 4));
  float* ebA  = (float*)(ws + alloc(NR * 4));
  float* chA  = (float*)(ws + alloc(NCH * OUT_F * 4));
  float* chB  = (float*)(ws + alloc(NCH * OUT_F * 4));
  float* bsA  = (float*)(ws + alloc(NCH * OUT_F * 4));
  float* bsB  = (float*)(ws + alloc(NCH * OUT_F * 4));

  k_prep<<<4096 + 1024, 256, 0, stream>>>(feat_edge, feat_edge_a, att, weight, s1, s2, B3t);
  k_gemm<<<1024, 256, 0, stream>>>(feat_node_a, B3t, Wh);
  k_rank<<<NR / 8, 256, 0, stream>>>(s2, s2s, perm, eaA, ebA);
  k_scan<<<1, 1024, 0, stream>>>(eaA, ebA, sufa, preb);
  k_passA<<<dim3(NCH, 2), 256, 0, stream>>>(Wh, eaA, ebA, perm, chA, chB);
  k_passB<<<NCH, 256, 0, stream>>>(chA, chB, bsA, bsB);
  k_passC<<<dim3(NCH, 2), 256, 0, stream>>>(Wh, eaA, ebA, perm, bsA, bsB, SufA, PreB);
  k_final<<<NR / 4, 256, 0, stream>>>(s1, s2s, sufa, preb, SufA, PreB, out);
}